// Round 3
// baseline (1227.403 us; speedup 1.0000x reference)
//
#include <hip/hip_runtime.h>
#include <stdint.h>

#define BATCH   8192
#define HALL    4096
#define TPB     256
#define PERT    16                    // HALL / TPB items per thread
#define EPS     10
#define BH      33554432u             // BATCH*HALL = 2^25
#define NCH     4                     // interleaved RNG chains per inner iter

// ---- JAX threefry2x32, partitionable mode, key = (0, 42) -----------------
// bits[L] = o0 ^ o1, (o0,o1) = threefry2x32(key, (0, L)); L < 2^32 here.
// rotl as v_alignbit_b32 (1 VALU op).
__device__ __forceinline__ uint32_t rotl32(uint32_t x, int r) {
    return __builtin_amdgcn_alignbit(x, x, 32 - r);
}

// 4-wide interleaved threefry round / key-injection (static unroll -> regs)
#define TF_R4(r)  { _Pragma("unroll") for (int k = 0; k < NCH; k++) { \
                      x0[k] += x1[k]; x1[k] = rotl32(x1[k], (r)); x1[k] ^= x0[k]; } }
#define TF_I4(ca, cb) { _Pragma("unroll") for (int k = 0; k < NCH; k++) { \
                      x0[k] += (ca); x1[k] += (cb); } }

// --------------------------------------------------------------------------
// Sampling key (max-form): argmax_h p/a == argmax_h t,  t = log2(u) * (1/p).
// Exact negation of the min-form q = (-log2 u)*(1/p): ordering + tie rules
// identical. u==0 -> log2 = -inf -> t = -inf -> never selected (matches the
// reference's tiny-clamp path, whose enormous -log(tiny) also never wins).
__global__ __launch_bounds__(TPB, 2)
void reinforce_kernel(const float* __restrict__ X, const float* __restrict__ W,
                      const float* __restrict__ bias, int* __restrict__ out) {
#pragma clang fp contract(off)
    __shared__ float s_ip[HALL];      // per-item 1/p = s_split/ex (own-thread use)
    __shared__ float s_rm[3][4];      // per-split max, per wave
    __shared__ float s_rs[3][4];      // per-split sum, per wave
    __shared__ float s_rv[EPS + 1][4];// 10 eps t-keys (max) + best-p (max), per wave
    __shared__ int   s_ri[EPS + 1][4];

    const int b   = blockIdx.x;
    const int tid = threadIdx.x;
    const int wv  = tid >> 6;
    const int ln  = tid & 63;
    const float* xr = X + (size_t)b * (HALL * 3);

    const float w00 = W[0], w01 = W[1], w02 = W[2], bb0 = bias[0];
    const float w10 = W[3], w11 = W[4], w12 = W[5], bb1 = bias[1];
    const float w20 = W[6], w21 = W[7], w22 = W[8], bb2 = bias[2];

    // ---- logits: thread owns h = tid + 256*j ; split: j<8 ->0, j<12 ->1, else 2
    float lg[PERT];
#pragma unroll
    for (int j = 0; j < PERT; j++) {
        int h = tid + j * TPB;
        float x0 = xr[3 * h], x1 = xr[3 * h + 1], x2 = xr[3 * h + 2];
        float wa, wb, wc, bb;
        if (j < 8)       { wa = w00; wb = w01; wc = w02; bb = bb0; }
        else if (j < 12) { wa = w10; wb = w11; wc = w12; bb = bb1; }
        else             { wa = w20; wb = w21; wc = w22; bb = bb2; }
        lg[j] = ((x0 * wa + x1 * wb) + x2 * wc) + bb;
    }

    // ---- per-split max (fused 3-value wave reduce, 1 sync)
    float pm0 = -INFINITY, pm1 = -INFINITY, pm2 = -INFINITY;
#pragma unroll
    for (int j = 0; j < PERT; j++) {
        if (j < 8)       pm0 = fmaxf(pm0, lg[j]);
        else if (j < 12) pm1 = fmaxf(pm1, lg[j]);
        else             pm2 = fmaxf(pm2, lg[j]);
    }
    for (int off = 32; off; off >>= 1) {
        pm0 = fmaxf(pm0, __shfl_down(pm0, off, 64));
        pm1 = fmaxf(pm1, __shfl_down(pm1, off, 64));
        pm2 = fmaxf(pm2, __shfl_down(pm2, off, 64));
    }
    if (ln == 0) { s_rm[0][wv] = pm0; s_rm[1][wv] = pm1; s_rm[2][wv] = pm2; }
    __syncthreads();
    const float m0 = fmaxf(fmaxf(s_rm[0][0], s_rm[0][1]), fmaxf(s_rm[0][2], s_rm[0][3]));
    const float m1 = fmaxf(fmaxf(s_rm[1][0], s_rm[1][1]), fmaxf(s_rm[1][2], s_rm[1][3]));
    const float m2 = fmaxf(fmaxf(s_rm[2][0], s_rm[2][1]), fmaxf(s_rm[2][2], s_rm[2][3]));

    // ---- per-split sum of exp(l - m) (fused 3-value wave reduce, 1 sync)
    float ex[PERT];
    float ps0 = 0.f, ps1 = 0.f, ps2 = 0.f;
#pragma unroll
    for (int j = 0; j < PERT; j++) {
        float m = (j < 8) ? m0 : (j < 12) ? m1 : m2;
        float e = expf(lg[j] - m);
        ex[j] = e;
        if (j < 8)       ps0 += e;
        else if (j < 12) ps1 += e;
        else             ps2 += e;
    }
    for (int off = 32; off; off >>= 1) {
        ps0 += __shfl_down(ps0, off, 64);
        ps1 += __shfl_down(ps1, off, 64);
        ps2 += __shfl_down(ps2, off, 64);
    }
    if (ln == 0) { s_rs[0][wv] = ps0; s_rs[1][wv] = ps1; s_rs[2][wv] = ps2; }
    __syncthreads();
    const float s0 = ((s_rs[0][0] + s_rs[0][1]) + s_rs[0][2]) + s_rs[0][3];
    const float s1 = ((s_rs[1][0] + s_rs[1][1]) + s_rs[1][2]) + s_rs[1][3];
    const float s2 = ((s_rs[2][0] + s_rs[2][1]) + s_rs[2][2]) + s_rs[2][3];

    // ---- best = argmax p (via p~ = ex * (1/s)); stash 1/p = s/ex in LDS
    const float is0 = 1.0f / s0, is1 = 1.0f / s1, is2 = 1.0f / s2;
    float bv = -INFINITY; int bi = 0;
#pragma unroll
    for (int j = 0; j < PERT; j++) {
        float sS  = (j < 8) ? s0  : (j < 12) ? s1  : s2;
        float isS = (j < 8) ? is0 : (j < 12) ? is1 : is2;
        float pt = ex[j] * isS;
        int h = tid + j * TPB;
        if (pt > bv) { bv = pt; bi = h; }   // ascending h => strict > keeps first idx
        s_ip[h] = sS / ex[j];               // exact-rounded 1/p; own-thread use only
    }

    // ---- epsilon sampling: outer e rolled (uniform), inner 4-chain interleave.
    // Per e: per-thread running max (t, idx); wave-reduce inside the loop.
    const uint32_t tb = (uint32_t)b * (uint32_t)HALL + (uint32_t)tid;
    const uint32_t ks2p = 0x1BD11BDAu ^ 42u;

#pragma unroll 1
    for (int e = 0; e < EPS; e++) {
        const uint32_t eoff = ((uint32_t)e << 25) + 42u;   // e*BH + ks1, uniform->SGPR
        float tmax = -INFINITY; int imax = 0x7fffffff;

#pragma unroll 1
        for (int jj = 0; jj < PERT; jj += NCH) {
            uint32_t x0[NCH], x1[NCH];
            float ip[NCH];
#pragma unroll
            for (int k = 0; k < NCH; k++) {
                int h = tid + (jj + k) * TPB;
                ip[k] = s_ip[h];                       // own element, no sync needed
                x0[k] = 0u;                            // counter hi word + ks0
                x1[k] = tb + (uint32_t)((jj + k) * TPB) + eoff;  // cnt + e*BH + 42
            }
            TF_R4(13) TF_R4(15) TF_R4(26) TF_R4(6)   TF_I4(42u,  ks2p + 1u)
            TF_R4(17) TF_R4(29) TF_R4(16) TF_R4(24)  TF_I4(ks2p, 2u)
            TF_R4(13) TF_R4(15) TF_R4(26) TF_R4(6)   TF_I4(0u,   42u + 3u)
            TF_R4(17) TF_R4(29) TF_R4(16) TF_R4(24)  TF_I4(42u,  ks2p + 4u)
            TF_R4(13) TF_R4(15) TF_R4(26) TF_R4(6)   TF_I4(ks2p, 5u)
#pragma unroll
            for (int k = 0; k < NCH; k++) {
                uint32_t bits = x0[k] ^ x1[k];
                // fb = (bits>>9) | 0x3F800000 == ((0x7F:bits) >> 9)[31:0]
                uint32_t fb = __builtin_amdgcn_alignbit(0x7Fu, bits, 9);
                float f = __uint_as_float(fb) - 1.0f;   // [0,1), multiple of 2^-23
                float t = __log2f(f) * ip[k];           // = -q; maximize
                int h = tid + (jj + k) * TPB;
                if (t > tmax) { tmax = t; imax = h; }   // ascending h keeps first
            }
        }

        // wave-reduce (max t, lowest idx on tie); store per-wave partial
        for (int off = 32; off; off >>= 1) {
            float tv = __shfl_down(tmax, off, 64);
            int   ti = __shfl_down(imax, off, 64);
            if (tv > tmax || (tv == tmax && ti < imax)) { tmax = tv; imax = ti; }
        }
        if (ln == 0) { s_rv[e][wv] = tmax; s_ri[e][wv] = imax; }
    }

    // ---- best (max p, idx) wave-reduce
    {
        float r = bv; int i = bi;
        for (int off = 32; off; off >>= 1) {
            float rv = __shfl_down(r, off, 64);
            int   ri = __shfl_down(i, off, 64);
            if (rv > r || (rv == r && ri < i)) { r = rv; i = ri; }
        }
        if (ln == 0) { s_rv[EPS][wv] = r; s_ri[EPS][wv] = i; }
    }
    __syncthreads();

    if (tid == 0) {
        int samp[EPS];
#pragma unroll
        for (int e = 0; e < EPS; e++) {
            float t = s_rv[e][0]; int i = s_ri[e][0];
#pragma unroll
            for (int w = 1; w < 4; w++) {
                float tv = s_rv[e][w]; int ri = s_ri[e][w];
                if (tv > t || (tv == t && ri < i)) { t = tv; i = ri; }
            }
            samp[e] = i;
        }
        float r = s_rv[EPS][0]; int best = s_ri[EPS][0];
#pragma unroll
        for (int w = 1; w < 4; w++) {
            float rv = s_rv[EPS][w]; int ri = s_ri[EPS][w];
            if (rv > r || (rv == r && ri < best)) { r = rv; best = ri; }
        }
        bool hit = false;
#pragma unroll
        for (int k = 0; k < EPS; k++) hit = hit || (samp[k] == best);
        out[b] = hit ? best : samp[EPS - 1];
    }
}

extern "C" void kernel_launch(void* const* d_in, const int* in_sizes, int n_in,
                              void* d_out, int out_size, void* d_ws, size_t ws_size,
                              hipStream_t stream) {
    const float* X    = (const float*)d_in[0];   // (8192, 12288) f32
    const float* W    = (const float*)d_in[1];   // (3, 3) f32
    const float* bias = (const float*)d_in[2];   // (3,) f32
    int* out = (int*)d_out;                      // (8192,) int32 actions
    (void)in_sizes; (void)n_in; (void)d_ws; (void)ws_size; (void)out_size;

    reinforce_kernel<<<BATCH, TPB, 0, stream>>>(X, W, bias, out);
}

// Round 4
// 1038.599 us; speedup vs baseline: 1.1818x; 1.1818x over previous
//
#include <hip/hip_runtime.h>
#include <stdint.h>

#define BATCH   8192
#define HALL    4096
#define TPB     256
#define PERT    16                    // consecutive items per thread
#define EPS     10

// ---- JAX threefry2x32, partitionable mode, key = (0, 42) -----------------
// bits[L] = o0 ^ o1, (o0,o1) = threefry2x32(key, (0, L)); L < 2^32 here.
// rotl as v_alignbit_b32 (1 VALU op).
__device__ __forceinline__ uint32_t rotl32(uint32_t x, int r) {
    return __builtin_amdgcn_alignbit(x, x, 32 - r);
}

__device__ __forceinline__ uint32_t threefry_bits_k42(uint32_t lo) {
    const uint32_t ks0 = 0u;
    const uint32_t ks1 = 42u;
    const uint32_t ks2 = 0x1BD11BDAu ^ 42u;
    uint32_t x0 = 0u + ks0;
    uint32_t x1 = lo + ks1;
#define TF_R(r) { x0 += x1; x1 = rotl32(x1, r); x1 ^= x0; }
    TF_R(13) TF_R(15) TF_R(26) TF_R(6)   x0 += ks1; x1 += ks2 + 1u;
    TF_R(17) TF_R(29) TF_R(16) TF_R(24)  x0 += ks2; x1 += ks0 + 2u;
    TF_R(13) TF_R(15) TF_R(26) TF_R(6)   x0 += ks0; x1 += ks1 + 3u;
    TF_R(17) TF_R(29) TF_R(16) TF_R(24)  x0 += ks1; x1 += ks2 + 4u;
    TF_R(13) TF_R(15) TF_R(26) TF_R(6)   x0 += ks2; x1 += ks0 + 5u;
#undef TF_R
    return x0 ^ x1;
}

// --------------------------------------------------------------------------
// h = 16*tid + k (consecutive items per thread):
//  - X loads become 12x float4 per thread, fully coalesced
//  - split is uniform per thread: tid<128 -> 0 (waves 0-1), wave2 -> 1, wave3 -> 2
//  - ip[16] lives in registers (k-loop fully unrolled, static indexing)
// Sampling key (max-form): argmax_h p/a == argmax_h t, t = log2(u)*(1/p).
// u==0 -> t = -inf -> never selected (matches reference tiny-clamp path).
__global__ __launch_bounds__(TPB, 8)   // cap VGPR at 64 -> 32 waves/CU
void reinforce_kernel(const float* __restrict__ X, const float* __restrict__ W,
                      const float* __restrict__ bias, int* __restrict__ out) {
#pragma clang fp contract(off)
    __shared__ float s_rm[4];          // per-wave max partial
    __shared__ float s_rs[4];          // per-wave sum partial
    __shared__ float s_rv[EPS + 1][4]; // 10 eps t-keys (max) + best-p (max)
    __shared__ int   s_ri[EPS + 1][4];

    const int b   = blockIdx.x;
    const int tid = threadIdx.x;
    const int wv  = tid >> 6;
    const int ln  = tid & 63;
    const int sp  = (wv < 2) ? 0 : (wv - 1);   // wave-uniform split id

    const float wa = W[3 * sp + 0], wb = W[3 * sp + 1], wc = W[3 * sp + 2];
    const float bb = bias[sp];

    // ---- logits: 12 float4 loads (48 consecutive floats = items 16*tid..+15)
    const float4* x4 = (const float4*)(X + (size_t)b * (HALL * 3)) + (size_t)tid * 12;
    float lg[PERT];
#pragma unroll
    for (int c = 0; c < 4; c++) {
        float4 a0 = x4[3 * c + 0];
        float4 a1 = x4[3 * c + 1];
        float4 a2 = x4[3 * c + 2];
        lg[4 * c + 0] = ((a0.x * wa + a0.y * wb) + a0.z * wc) + bb;
        lg[4 * c + 1] = ((a0.w * wa + a1.x * wb) + a1.y * wc) + bb;
        lg[4 * c + 2] = ((a1.z * wa + a1.w * wb) + a2.x * wc) + bb;
        lg[4 * c + 3] = ((a2.y * wa + a2.z * wb) + a2.w * wc) + bb;
    }

    // ---- split max: thread-local then per-wave reduce; combine waves 0+1
    float pm = lg[0];
#pragma unroll
    for (int k = 1; k < PERT; k++) pm = fmaxf(pm, lg[k]);
    for (int off = 32; off; off >>= 1) pm = fmaxf(pm, __shfl_down(pm, off, 64));
    if (ln == 0) s_rm[wv] = pm;
    __syncthreads();
    const float m = (wv < 2) ? fmaxf(s_rm[0], s_rm[1]) : s_rm[wv];

    // ---- split sum of exp(l - m)
    float ex[PERT];
    float ps = 0.f;
#pragma unroll
    for (int k = 0; k < PERT; k++) { float e = expf(lg[k] - m); ex[k] = e; ps += e; }
    for (int off = 32; off; off >>= 1) ps += __shfl_down(ps, off, 64);
    if (ln == 0) s_rs[wv] = ps;
    __syncthreads();
    const float s = (wv < 2) ? (s_rs[0] + s_rs[1]) : s_rs[wv];

    // ---- best = argmax p (p~ = ex*(1/s)); ip[k] = 1/p = s/ex in REGISTERS
    const float is = 1.0f / s;
    float ip[PERT];
    float bv = -INFINITY; int bk = 0;
#pragma unroll
    for (int k = 0; k < PERT; k++) {
        float pt = ex[k] * is;
        if (pt > bv) { bv = pt; bk = k; }  // ascending k => strict > keeps first
        ip[k] = s / ex[k];                 // exact-rounded 1/p
    }

    // ---- epsilon sampling: fully unrolled 16 items x 10 eps, all in registers.
    // counter L = e*2^25 + b*4096 + 16*tid + k  (BATCH*HALL = 2^25)
    const uint32_t tb2 = (uint32_t)b * (uint32_t)HALL + (uint32_t)tid * (uint32_t)PERT;
    const int hbase = tid * PERT;

    float qmv[EPS]; int qik[EPS];
#pragma unroll
    for (int e = 0; e < EPS; e++) { qmv[e] = -INFINITY; qik[e] = 0; }

#pragma unroll
    for (int k = 0; k < PERT; k++) {
        const float ipk = ip[k];           // static index -> register
#pragma unroll
        for (int e = 0; e < EPS; e++) {
            uint32_t bits = threefry_bits_k42(tb2 + (uint32_t)(k + (e << 25)));
            // fb = (bits>>9) | 0x3F800000 == ((0x7F:bits) >> 9)[31:0]
            uint32_t fb = __builtin_amdgcn_alignbit(0x7Fu, bits, 9);
            float f = __uint_as_float(fb) - 1.0f;   // [0,1), multiple of 2^-23
            float t = __log2f(f) * ipk;             // maximize t == minimize a/p
            if (t > qmv[e]) { qmv[e] = t; qik[e] = k; }  // k: inline-const cndmask
        }
    }

    // ---- tail: wave-reduce 10 eps (max t, lowest h on tie) + best; ONE sync
#pragma unroll
    for (int e = 0; e < EPS; e++) {
        float t = qmv[e];
        int   i = hbase + qik[e];
        for (int off = 32; off; off >>= 1) {
            float tv = __shfl_down(t, off, 64);
            int   ti = __shfl_down(i, off, 64);
            if (tv > t || (tv == t && ti < i)) { t = tv; i = ti; }
        }
        if (ln == 0) { s_rv[e][wv] = t; s_ri[e][wv] = i; }
    }
    {
        float r = bv; int i = hbase + bk;
        for (int off = 32; off; off >>= 1) {
            float rv = __shfl_down(r, off, 64);
            int   ri = __shfl_down(i, off, 64);
            if (rv > r || (rv == r && ri < i)) { r = rv; i = ri; }
        }
        if (ln == 0) { s_rv[EPS][wv] = r; s_ri[EPS][wv] = i; }
    }
    __syncthreads();

    if (tid == 0) {
        int samp[EPS];
#pragma unroll
        for (int e = 0; e < EPS; e++) {
            float t = s_rv[e][0]; int i = s_ri[e][0];
#pragma unroll
            for (int w = 1; w < 4; w++) {
                float tv = s_rv[e][w]; int ri = s_ri[e][w];
                if (tv > t || (tv == t && ri < i)) { t = tv; i = ri; }
            }
            samp[e] = i;
        }
        float r = s_rv[EPS][0]; int best = s_ri[EPS][0];
#pragma unroll
        for (int w = 1; w < 4; w++) {
            float rv = s_rv[EPS][w]; int ri = s_ri[EPS][w];
            if (rv > r || (rv == r && ri < best)) { r = rv; best = ri; }
        }
        bool hit = false;
#pragma unroll
        for (int k = 0; k < EPS; k++) hit = hit || (samp[k] == best);
        out[b] = hit ? best : samp[EPS - 1];
    }
}

extern "C" void kernel_launch(void* const* d_in, const int* in_sizes, int n_in,
                              void* d_out, int out_size, void* d_ws, size_t ws_size,
                              hipStream_t stream) {
    const float* X    = (const float*)d_in[0];   // (8192, 12288) f32
    const float* W    = (const float*)d_in[1];   // (3, 3) f32
    const float* bias = (const float*)d_in[2];   // (3,) f32
    int* out = (int*)d_out;                      // (8192,) int32 actions
    (void)in_sizes; (void)n_in; (void)d_ws; (void)ws_size; (void)out_size;

    reinforce_kernel<<<BATCH, TPB, 0, stream>>>(X, W, bias, out);
}